// Round 1
// baseline (724.880 us; speedup 1.0000x reference)
//
#include <hip/hip_runtime.h>
#include <cmath>
#include <complex>
#include <vector>
#include <algorithm>

// ---------------------------------------------------------------------------
// Compile-time sparsity pattern for the real-basis Wigner-3j contraction.
//
// Real-basis selection rules (exact superset of the nonzeros):
//   |m3| in { |m1|+|m2| , ||m1|-|m2|| }
//   #negative-m indices among (m1,m2,m3) must be even  (valid because every
//   triple in TRIPLES has l1+l2+l3 even, making the (-i)^L phase real)
// => for each (m1,m2,|m3|) the sign of m3 is forced.
// ---------------------------------------------------------------------------

struct Entry {
  signed char l1, l2, l3;   // triple (host-side weight lookup)
  signed char m1, m2, m3;   // real-basis m indices (host-side weight lookup)
  signed char xi, yi, si;   // flat indices into x[16], y[16], acc[25]
};

constexpr int MAXE = 2048;

struct Pattern {
  Entry e[MAXE];
  int n;
};

constexpr Pattern build_pattern() {
  Pattern p{};
  p.n = 0;
  for (int l1 = 0; l1 <= 3; ++l1)
    for (int l2 = 0; l2 <= 3; ++l2)
      for (int m1 = -l1; m1 <= l1; ++m1)
        for (int m2 = -l2; m2 <= l2; ++m2) {
          int a1 = m1 < 0 ? -m1 : m1;
          int a2 = m2 < 0 ? -m2 : m2;
          int Ms = a1 + a2;
          int Md = a1 > a2 ? a1 - a2 : a2 - a1;
          int odd = ((m1 < 0 ? 1 : 0) + (m2 < 0 ? 1 : 0)) & 1;
          int lo = l1 > l2 ? l1 - l2 : l2 - l1;
          int hi = (l1 + l2 < 4) ? (l1 + l2) : 4;
          for (int l3 = lo; l3 <= hi; ++l3) {
            if ((l1 + l2 + l3) & 1) continue;   // parity rule of TRIPLES
            for (int c = 0; c < 2; ++c) {
              if (c == 1 && Md == Ms) continue; // dedupe when min(|m1|,|m2|)==0
              int M = (c == 0) ? Ms : Md;
              if (M > l3) continue;
              int m3 = 0;
              if (odd) {
                if (M == 0) continue;           // sin-parity forbids m3==0
                m3 = -M;
              } else {
                m3 = M;
              }
              p.e[p.n].l1 = (signed char)l1;
              p.e[p.n].l2 = (signed char)l2;
              p.e[p.n].l3 = (signed char)l3;
              p.e[p.n].m1 = (signed char)m1;
              p.e[p.n].m2 = (signed char)m2;
              p.e[p.n].m3 = (signed char)m3;
              p.e[p.n].xi = (signed char)(l1 * l1 + l1 + m1);
              p.e[p.n].yi = (signed char)(l2 * l2 + l2 + m2);
              p.e[p.n].si = (signed char)(l3 * l3 + l3 + m3);
              ++p.n;
            }
          }
        }
  return p;
}

constexpr Pattern PAT = build_pattern();
constexpr int NNZ = PAT.n;
static_assert(NNZ > 0 && NNZ < MAXE, "pattern size sanity");

// ---------------------------------------------------------------------------
// Host-side Wigner-3j (real basis) — exact port of the reference math.
// ---------------------------------------------------------------------------

typedef std::complex<double> cd;

static double factd(int n) {
  double r = 1.0;
  for (int i = 2; i <= n; ++i) r *= (double)i;
  return r;
}

static double su2_cg_coeff(int j1, int m1, int j2, int m2, int j3, int m3) {
  if (m3 != m1 + m2) return 0.0;
  int vmin = std::max(std::max(-j1 + j2 + m3, -j1 + m1), 0);
  int vmax = std::min(std::min(j2 + j3 + m1, j3 - j1 + j2), j3 + m3);
  if (vmax < vmin) return 0.0;
  double C = std::sqrt((2.0 * j3 + 1) * factd(j3 + j1 - j2) * factd(j3 - j1 + j2) *
                       factd(j1 + j2 - j3) * factd(j3 + m3) * factd(j3 - m3) /
                       (factd(j1 + j2 + j3 + 1) * factd(j1 - m1) * factd(j1 + m1) *
                        factd(j2 - m2) * factd(j2 + m2)));
  double S = 0.0;
  for (int v = vmin; v <= vmax; ++v) {
    double sgn = ((v + j2 + m2) % 2 == 0) ? 1.0 : -1.0;
    S += sgn * factd(j2 + j3 + m1 - v) * factd(j1 - m1 + v) /
         (factd(v) * factd(j3 - j1 + j2 - v) * factd(j3 + m3 - v) *
          factd(j1 - j2 - m3 + v));
  }
  return C * S;
}

static void real_to_complex(int l, cd Q[9][9]) {
  const double s2 = 1.0 / std::sqrt(2.0);
  for (int i = 0; i < 9; ++i)
    for (int j = 0; j < 9; ++j) Q[i][j] = cd(0.0, 0.0);
  for (int m = -l; m < 0; ++m) {
    Q[l + m][l - m] = cd(s2, 0.0);      // column l + |m|
    Q[l + m][l + m] = cd(0.0, -s2);     // column l - |m|
  }
  Q[l][l] = cd(1.0, 0.0);
  for (int m = 1; m <= l; ++m) {
    double sgn = (m % 2 == 0) ? 1.0 : -1.0;
    Q[l + m][l + m] = cd(sgn * s2, 0.0);
    Q[l + m][l - m] = cd(0.0, sgn * s2);
  }
  cd ph(1.0, 0.0);
  for (int i = 0; i < l; ++i) ph *= cd(0.0, -1.0);   // (-i)^l
  for (int i = 0; i < 2 * l + 1; ++i)
    for (int j = 0; j < 2 * l + 1; ++j) Q[i][j] *= ph;
}

// W flattened as [7][7][9]
static void wigner3j(int l1, int l2, int l3, double* W) {
  const int n1 = 2 * l1 + 1, n2 = 2 * l2 + 1, n3 = 2 * l3 + 1;
  double cg[7][7][9] = {};
  for (int m1 = -l1; m1 <= l1; ++m1)
    for (int m2 = -l2; m2 <= l2; ++m2) {
      int m3 = m1 + m2;
      if (-l3 <= m3 && m3 <= l3)
        cg[l1 + m1][l2 + m2][l3 + m3] = su2_cg_coeff(l1, m1, l2, m2, l3, m3);
    }
  cd Q1[9][9], Q2[9][9], Q3[9][9];
  real_to_complex(l1, Q1);
  real_to_complex(l2, Q2);
  real_to_complex(l3, Q3);
  double nrm = 0.0;
  for (int j = 0; j < n1; ++j)
    for (int lc = 0; lc < n2; ++lc)
      for (int n = 0; n < n3; ++n) {
        cd s(0.0, 0.0);
        for (int i = 0; i < n1; ++i)
          for (int k = 0; k < n2; ++k)
            for (int m = 0; m < n3; ++m) {
              double c = cg[i][k][m];
              if (c != 0.0) s += Q1[i][j] * Q2[k][lc] * Q3[m][n] * c;
            }
        double re = s.real();
        W[(j * 7 + lc) * 9 + n] = re;
        nrm += re * re;
      }
  nrm = std::sqrt(nrm);
  if (nrm > 0.0)
    for (int i = 0; i < 7 * 7 * 9; ++i) W[i] /= nrm;
}

static const std::vector<float>& host_weights() {
  static const std::vector<float> v = [] {
    std::vector<float> w((size_t)NNZ);
    std::vector<double> wt((size_t)4 * 4 * 5 * 7 * 7 * 9, 0.0);
    bool have[4][4][5] = {};
    for (int k = 0; k < NNZ; ++k) {
      const Entry& e = PAT.e[k];
      int l1 = e.l1, l2 = e.l2, l3 = e.l3;
      double* W = &wt[(((size_t)l1 * 4 + l2) * 5 + l3) * (7 * 7 * 9)];
      if (!have[l1][l2][l3]) {
        wigner3j(l1, l2, l3, W);
        have[l1][l2][l3] = true;
      }
      w[k] = (float)W[((l1 + e.m1) * 7 + (l2 + e.m2)) * 9 + (l3 + e.m3)];
    }
    return w;
  }();
  return v;
}

// ---------------------------------------------------------------------------
// Kernel: one thread per (node, channel) pair.
//   x[16], y[16] via aligned float4 loads (pair stride = 64 B).
//   Fully-unrolled 525-entry FMA chain; weight loads are wave-uniform at
//   compile-time-constant offsets -> scalar loads.
//   Output staged through LDS -> fully coalesced float4 stores.
// ---------------------------------------------------------------------------

__global__ __launch_bounds__(256) void cp3j_kernel(const float* __restrict__ t1,
                                                   const float* __restrict__ t2,
                                                   const float* __restrict__ w,
                                                   float* __restrict__ out) {
  __shared__ float4 lds4[1600];                    // 256 pairs * 25 floats
  float* lds = reinterpret_cast<float*>(lds4);
  const int t = threadIdx.x;
  const int pair = blockIdx.x * 256 + t;

  const float4* a4 = reinterpret_cast<const float4*>(t1) + (size_t)pair * 4;
  const float4* b4 = reinterpret_cast<const float4*>(t2) + (size_t)pair * 4;
  float x[16], y[16];
#pragma unroll
  for (int i = 0; i < 4; ++i) {
    float4 va = a4[i];
    float4 vb = b4[i];
    x[4 * i + 0] = va.x; x[4 * i + 1] = va.y; x[4 * i + 2] = va.z; x[4 * i + 3] = va.w;
    y[4 * i + 0] = vb.x; y[4 * i + 1] = vb.y; y[4 * i + 2] = vb.z; y[4 * i + 3] = vb.w;
  }

  float acc[25];
#pragma unroll
  for (int s = 0; s < 25; ++s) acc[s] = 0.0f;

#pragma unroll
  for (int k = 0; k < NNZ; ++k) {
    acc[PAT.e[k].si] += w[k] * (x[PAT.e[k].xi] * y[PAT.e[k].yi]);
  }

#pragma unroll
  for (int s = 0; s < 25; ++s) lds[t * 25 + s] = acc[s];
  __syncthreads();

  float4* o4 = reinterpret_cast<float4*>(out + (size_t)blockIdx.x * 6400);
#pragma unroll
  for (int i = 0; i < 6; ++i) o4[t + i * 256] = lds4[t + i * 256];
  if (t < 64) o4[1536 + t] = lds4[1536 + t];
}

// ---------------------------------------------------------------------------

extern "C" void kernel_launch(void* const* d_in, const int* in_sizes, int n_in,
                              void* d_out, int out_size, void* d_ws, size_t ws_size,
                              hipStream_t stream) {
  const float* t1 = (const float*)d_in[0];
  const float* t2 = (const float*)d_in[1];
  float* out = (float*)d_out;
  float* wdev = (float*)d_ws;

  const std::vector<float>& hw = host_weights();
  // d_ws is re-poisoned before every timed launch -> upload weights inside the
  // graph every call (H2D memcpy captures as a graph memcpy node).
  hipMemcpyAsync(wdev, hw.data(), (size_t)NNZ * sizeof(float),
                 hipMemcpyHostToDevice, stream);

  const int pairs = in_sizes[0] / 16;      // 50000 * 64 = 3,200,000
  const int blocks = pairs / 256;          // exactly 12500, no tail
  cp3j_kernel<<<blocks, 256, 0, stream>>>(t1, t2, wdev, out);
}